// Round 1
// baseline (324.402 us; speedup 1.0000x reference)
//
#include <hip/hip_runtime.h>

// Problem constants (fixed by the reference):
//   B=4, C=64, NX=512, NY=512, N = 120000 pillars
#define NXC 512
#define NYC 512
#define CC  64
#define BC  4

// ---------------------------------------------------------------------------
// Kernel 1: zero the pillar-index map in workspace (4 MB = B*NX*NY int32).
// d_ws is poisoned 0xAA before every timed launch, so this must run each call.
__global__ void pp_zero_map(int4* __restrict__ map4, int n4) {
    int i = blockIdx.x * blockDim.x + threadIdx.x;
    if (i < n4) map4[i] = make_int4(0, 0, 0, 0);
}

// ---------------------------------------------------------------------------
// Kernel 2: scatter pillar index n+1 into map[b*NX*NY + x*NY + y].
// coords are unique per (b,x,y) so no write races.
__global__ void pp_build_map(const int* __restrict__ coords, int* __restrict__ map, int N) {
    int n = blockIdx.x * blockDim.x + threadIdx.x;
    if (n >= N) return;
    int4 c = *(const int4*)(coords + 4 * (size_t)n);  // (b, z, y, x)
    int b = c.x, y = c.z, x = c.w;
    map[((size_t)b * NXC + x) * NYC + y] = n + 1;
}

// ---------------------------------------------------------------------------
// Kernel 3: gather. One block per (b, x) output row; 256 threads.
// Thread t owns y4 = (t&127)*4 (4 consecutive y's) and c-parity (t>>7),
// loops c over its parity class: every iteration the wave writes coalesced
// float4s (full 64B lines across 4 adjacent threads).
// Map entries are read once per thread (int4, coalesced). vf rows (256 B)
// are scattered reads but stay resident in L1/L2 across the 32 c-iterations
// of this block, and each pillar belongs to exactly one block -> ~1x HBM read.
__global__ void pp_gather(const float* __restrict__ vf,
                          const int* __restrict__ map,
                          float* __restrict__ out) {
    int bx = blockIdx.x;            // 0 .. B*NX-1
    int t  = threadIdx.x;           // 0 .. 255
    int b  = bx >> 9;               // /512
    int x  = bx & (NXC - 1);

    int c0 = t >> 7;                // 0 or 1
    int y4 = (t & 127) << 2;        // 0,4,...,508

    int4 nn = *(const int4*)(map + (size_t)bx * NYC + y4);

    const float* v0 = vf + (size_t)(nn.x - 1) * CC;
    const float* v1 = vf + (size_t)(nn.y - 1) * CC;
    const float* v2 = vf + (size_t)(nn.z - 1) * CC;
    const float* v3 = vf + (size_t)(nn.w - 1) * CC;

    float* obase = out + ((size_t)b * CC * NXC + x) * NYC + y4;

    #pragma unroll 4
    for (int c = c0; c < CC; c += 2) {
        float4 v;
        v.x = nn.x ? v0[c] : 0.0f;
        v.y = nn.y ? v1[c] : 0.0f;
        v.z = nn.z ? v2[c] : 0.0f;
        v.w = nn.w ? v3[c] : 0.0f;
        *(float4*)(obase + (size_t)c * (NXC * NYC)) = v;
    }
}

extern "C" void kernel_launch(void* const* d_in, const int* in_sizes, int n_in,
                              void* d_out, int out_size, void* d_ws, size_t ws_size,
                              hipStream_t stream) {
    const float* vf     = (const float*)d_in[0];
    const int*   coords = (const int*)d_in[1];
    // d_in[2] = batch_size scalar (fixed at 4; dims are compile-time constants)

    float* out = (float*)d_out;
    int*   map = (int*)d_ws;                       // 4 MB: B*NX*NY int32

    const int N = in_sizes[0] / CC;                // 120000 pillars
    const int MAPN  = BC * NXC * NYC;              // 1,048,576
    const int MAPN4 = MAPN / 4;                    // 262,144 int4s

    pp_zero_map<<<(MAPN4 + 255) / 256, 256, 0, stream>>>((int4*)map, MAPN4);
    pp_build_map<<<(N + 255) / 256, 256, 0, stream>>>(coords, map, N);
    pp_gather<<<BC * NXC, 256, 0, stream>>>(vf, map, out);
}

// Round 3
// 295.137 us; speedup vs baseline: 1.0992x; 1.0992x over previous
//
#include <hip/hip_runtime.h>

// Problem constants (fixed by the reference):
//   B=4, C=64, NX=512, NY=512, N = 120000 pillars
#define NXC 512
#define NYC 512
#define CC  64
#define BC  4
#define PLANE (NXC * NYC)   // 262144 floats per (b,c) plane

typedef float v4f __attribute__((ext_vector_type(4)));  // native vector: OK for nontemporal builtins

// ---------------------------------------------------------------------------
// Kernel 1: zero the pillar-index map (4 MB) PLUS a 256 B zero-row appended
// right after it (used as the branchless source for empty pillars).
// d_ws is poisoned 0xAA before every timed launch, so this must run each call.
__global__ void pp_zero_map(int4* __restrict__ map4, int n4) {
    int i = blockIdx.x * blockDim.x + threadIdx.x;
    if (i < n4) map4[i] = make_int4(0, 0, 0, 0);
}

// ---------------------------------------------------------------------------
// Kernel 2: scatter pillar index n+1 into map[b*NX*NY + x*NY + y].
// coords are unique per (b,x,y) so no write races.
__global__ void pp_build_map(const int* __restrict__ coords, int* __restrict__ map, int N) {
    int n = blockIdx.x * blockDim.x + threadIdx.x;
    if (n >= N) return;
    int4 c = *(const int4*)(coords + 4 * (size_t)n);  // (b, z, y, x)
    map[((size_t)c.x * NXC + c.w) * NYC + c.z] = n + 1;
}

// ---------------------------------------------------------------------------
// Kernel 3: gather. One block per (b, x) output row; 256 threads.
// Thread t owns 4 consecutive y's (y4 = (t&127)*4) and a 32-wide c-half
// (c0 = (t>>7)*32). It reads its 4 pillar rows as float4s (vectorized,
// 8 loads/pillar), transposes 4x4 in registers, and writes 4 coalesced
// v4f's per group into the c-planes. Empty pillars read a shared 256 B
// zero-row (always L1-resident) -> fully branchless inner loop.
// Output stores are non-temporal: 256 MiB write-once stream should not
// evict the vf/map working set from L2.
__global__ void __launch_bounds__(256) pp_gather(const float* __restrict__ vf,
                                                 const int* __restrict__ map,
                                                 const float* __restrict__ zrow,
                                                 float* __restrict__ out) {
    int bx = blockIdx.x;            // 0 .. B*NX-1
    int t  = threadIdx.x;           // 0 .. 255
    int b  = bx >> 9;               // /512
    int x  = bx & (NXC - 1);

    int c0 = (t >> 7) << 5;         // 0 or 32
    int y4 = (t & 127) << 2;        // 0,4,...,508

    int4 nn = *(const int4*)(map + (size_t)bx * NYC + y4);

    const float* p0 = nn.x ? vf + (size_t)(nn.x - 1) * CC : zrow;
    const float* p1 = nn.y ? vf + (size_t)(nn.y - 1) * CC : zrow;
    const float* p2 = nn.z ? vf + (size_t)(nn.z - 1) * CC : zrow;
    const float* p3 = nn.w ? vf + (size_t)(nn.w - 1) * CC : zrow;

    float* ob = out + ((size_t)(b * CC + c0) * NXC + x) * NYC + y4;

    #pragma unroll
    for (int cg = 0; cg < 8; ++cg) {
        int c = c0 + cg * 4;
        v4f va = *(const v4f*)(p0 + c);   // pillar @ y4+0, channels c..c+3
        v4f vb = *(const v4f*)(p1 + c);   // pillar @ y4+1
        v4f vc = *(const v4f*)(p2 + c);   // pillar @ y4+2
        v4f vd = *(const v4f*)(p3 + c);   // pillar @ y4+3
        float* o = ob + (size_t)cg * 4 * PLANE;
        v4f s0 = {va.x, vb.x, vc.x, vd.x};  // plane c
        v4f s1 = {va.y, vb.y, vc.y, vd.y};  // plane c+1
        v4f s2 = {va.z, vb.z, vc.z, vd.z};  // plane c+2
        v4f s3 = {va.w, vb.w, vc.w, vd.w};  // plane c+3
        __builtin_nontemporal_store(s0, (v4f*)(o));
        __builtin_nontemporal_store(s1, (v4f*)(o + PLANE));
        __builtin_nontemporal_store(s2, (v4f*)(o + 2 * (size_t)PLANE));
        __builtin_nontemporal_store(s3, (v4f*)(o + 3 * (size_t)PLANE));
    }
}

extern "C" void kernel_launch(void* const* d_in, const int* in_sizes, int n_in,
                              void* d_out, int out_size, void* d_ws, size_t ws_size,
                              hipStream_t stream) {
    const float* vf     = (const float*)d_in[0];
    const int*   coords = (const int*)d_in[1];
    // d_in[2] = batch_size scalar (fixed at 4; dims are compile-time constants)

    float* out  = (float*)d_out;
    int*   map  = (int*)d_ws;                      // 4 MB: B*NX*NY int32
    const int MAPN = BC * NXC * NYC;               // 1,048,576
    float* zrow = (float*)(map + MAPN);            // 256 B zero row after map

    const int N = in_sizes[0] / CC;                // 120000 pillars
    const int MAPN4 = MAPN / 4 + 16;               // int4s: map + 64-float zero row

    pp_zero_map<<<(MAPN4 + 255) / 256, 256, 0, stream>>>((int4*)map, MAPN4);
    pp_build_map<<<(N + 255) / 256, 256, 0, stream>>>(coords, map, N);
    pp_gather<<<BC * NXC, 256, 0, stream>>>(vf, map, zrow, out);
}